// Round 3
// baseline (674.905 us; speedup 1.0000x reference)
//
#include <hip/hip_runtime.h>
#include <hip/hip_fp16.h>
#include <stdint.h>

// ---------------------------------------------------------------------------
// GraphConv (planetoid-gcn-residual):
//   h   = norm * (x @ W.T + bias),  norm = rsqrt(1+deg)
//   out = norm * (spmm_add(adj,h) + h)
// R3 (743.6 -> 666.9 us): single atomic pass (rank), atomic-free scatter,
//   gemm LDS write-conflict XOR swizzle, agg split into 2 half-feature passes.
// R5: rank_kernel was top kernel (147 us) with VALUBusy 0.27% -> pure
//   atomic-latency bound (~1 us implied round-trip, ~21.5k in flight).
//   Change: 8 edges/thread -> 8 independent returning atomics per lane in
//   flight (~49k total). Predicted rank ~65-85 us, e2e ~590-610 us.
//   Everything else unchanged (one variable per experiment).
// ---------------------------------------------------------------------------

#define THREADS 256

typedef _Float16 half8 __attribute__((ext_vector_type(8)));
typedef float floatx4 __attribute__((ext_vector_type(4)));

// ---------------- rank pass: one atomic per edge, 8 edges/thread ----------------
__global__ void rank_kernel(const int* __restrict__ rows, int* __restrict__ cnt,
                            int* __restrict__ rank, int E) {
    int base = (blockIdx.x * THREADS + threadIdx.x) * 8;
    if (base + 7 < E) {
        int4 a = *(const int4*)(rows + base);
        int4 b = *(const int4*)(rows + base + 4);
        int4 ka, kb;
        ka.x = atomicAdd(&cnt[a.x], 1);
        ka.y = atomicAdd(&cnt[a.y], 1);
        ka.z = atomicAdd(&cnt[a.z], 1);
        ka.w = atomicAdd(&cnt[a.w], 1);
        kb.x = atomicAdd(&cnt[b.x], 1);
        kb.y = atomicAdd(&cnt[b.y], 1);
        kb.z = atomicAdd(&cnt[b.z], 1);
        kb.w = atomicAdd(&cnt[b.w], 1);
        *(int4*)(rank + base)     = ka;
        *(int4*)(rank + base + 4) = kb;
    } else {
        for (int i = base; i < E && i < base + 8; ++i)
            rank[i] = atomicAdd(&cnt[rows[i]], 1);
    }
}

// ---------------- 3-kernel exclusive scan over cnt[0..n) ----------------
__global__ void scanA(const int* __restrict__ cnt, int* __restrict__ rs,
                      int* __restrict__ bsums, int n) {
    __shared__ int s[THREADS];
    int tid  = threadIdx.x;
    int base = blockIdx.x * 1024 + tid * 4;
    int v0 = (base + 0 < n) ? cnt[base + 0] : 0;
    int v1 = (base + 1 < n) ? cnt[base + 1] : 0;
    int v2 = (base + 2 < n) ? cnt[base + 2] : 0;
    int v3 = (base + 3 < n) ? cnt[base + 3] : 0;
    int sum = v0 + v1 + v2 + v3;
    s[tid] = sum;
    __syncthreads();
    for (int off = 1; off < THREADS; off <<= 1) {
        int t = (tid >= off) ? s[tid - off] : 0;
        __syncthreads();
        s[tid] += t;
        __syncthreads();
    }
    int run = s[tid] - sum;
    if (base + 0 < n) rs[base + 0] = run;  run += v0;
    if (base + 1 < n) rs[base + 1] = run;  run += v1;
    if (base + 2 < n) rs[base + 2] = run;  run += v2;
    if (base + 3 < n) rs[base + 3] = run;
    if (tid == THREADS - 1) bsums[blockIdx.x] = s[THREADS - 1];
}

__global__ void scanB(int* __restrict__ bsums, int nb) {
    __shared__ int s[THREADS];
    int tid = threadIdx.x;
    int v = (tid < nb) ? bsums[tid] : 0;
    s[tid] = v;
    __syncthreads();
    for (int off = 1; off < THREADS; off <<= 1) {
        int t = (tid >= off) ? s[tid - off] : 0;
        __syncthreads();
        s[tid] += t;
        __syncthreads();
    }
    if (tid < nb) bsums[tid] = s[tid] - v;
}

__global__ void scanC(int* __restrict__ rs, const int* __restrict__ bsums, int n, int E) {
    int tid  = threadIdx.x;
    int base = blockIdx.x * 1024 + tid * 4;
    int add  = bsums[blockIdx.x];
    if (base + 0 < n) rs[base + 0] += add;
    if (base + 1 < n) rs[base + 1] += add;
    if (base + 2 < n) rs[base + 2] += add;
    if (base + 3 < n) rs[base + 3] += add;
    if (blockIdx.x == 0 && tid == 0) rs[n] = E;
}

// ---------------- atomic-free scatter using precomputed ranks ----------------
__global__ void scatter2(const int* __restrict__ rows, const int* __restrict__ cols,
                         const int* __restrict__ rank, const int* __restrict__ rs,
                         int* __restrict__ csr_col, int E) {
    int e = (blockIdx.x * THREADS + threadIdx.x) * 4;
    if (e + 3 < E) {
        int4 r4 = *(const int4*)(rows + e);
        int4 c4 = *(const int4*)(cols + e);
        int4 k4 = *(const int4*)(rank + e);
        csr_col[rs[r4.x] + k4.x] = c4.x;
        csr_col[rs[r4.y] + k4.y] = c4.y;
        csr_col[rs[r4.z] + k4.z] = c4.z;
        csr_col[rs[r4.w] + k4.w] = c4.w;
    } else {
        for (int i = e; i < E && i < e + 4; ++i)
            csr_col[rs[rows[i]] + rank[i]] = cols[i];
    }
}

// ---------------- W -> f16 B-fragment swizzle ----------------
__global__ void make_bswz(const float* __restrict__ W, half8* __restrict__ Bswz) {
    int t = blockIdx.x * THREADS + threadIdx.x;   // 8192 entries
    int n_tile = t >> 9;
    int k_step = (t >> 6) & 7;
    int lane   = t & 63;
    int q = lane >> 4, m16 = lane & 15;
    const float* src = W + (size_t)(n_tile * 16 + m16) * 256 + k_step * 32 + q * 8;
    half8 h;
#pragma unroll
    for (int j = 0; j < 8; j++) h[j] = (_Float16)src[j];
    Bswz[t] = h;
}

// LDS byte-address swizzle: spread k_step (bits 10-12) and q-parity (bit 8)
// into bits 4-7 so staging writes hit all banks (was ~32-way conflict).
__device__ __forceinline__ int As_swz(int b) {
    return b ^ ((((b >> 10) & 7) ^ (((b >> 8) & 1) << 3)) << 4);
}

// ---------------- f16 MFMA GEMM + bias + norm scale ----------------
// Block: 256 thr = 4 waves. Tile: 64 rows x 256 cols; wave w -> cols [64w,64w+64).
__global__ __launch_bounds__(THREADS) void gemm_mfma(
    const float* __restrict__ x, const half8* __restrict__ Bswz,
    const float* __restrict__ bias, const int* __restrict__ rs,
    _Float16* __restrict__ h16, int n) {
    __shared__ _Float16 As[4 * 8 * 64 * 8];   // 32 KB, A-frag layout (swizzled)
    int tid  = threadIdx.x;
    int row0 = blockIdx.x * 64;

    // stage x tile fp32 -> f16 into (swizzled) A-frag layout
#pragma unroll
    for (int i = 0; i < 16; i++) {
        int flat = i * THREADS + tid;
        int r  = flat >> 6;         // 0..63 row in tile
        int k  = (flat & 63) * 4;   // 0..252 step 4
        float4 v;
        if (row0 + r < n) v = *(const float4*)(x + (size_t)(row0 + r) * 256 + k);
        else { v.x = 0.f; v.y = 0.f; v.z = 0.f; v.w = 0.f; }
        int m_sub  = r >> 4;
        int k_step = k >> 5;
        int q      = (k >> 3) & 3;
        int j      = k & 7;         // 0 or 4
        int lane_w = (r & 15) + (q << 4);
        int entry  = (m_sub * 8 + k_step) * 64 + lane_w;
        union { _Float16 h[4]; uint2 u; } pk;
        pk.h[0] = (_Float16)v.x; pk.h[1] = (_Float16)v.y;
        pk.h[2] = (_Float16)v.z; pk.h[3] = (_Float16)v.w;
        *(uint2*)((char*)As + As_swz(entry * 16 + (j << 1))) = pk.u;
    }
    __syncthreads();

    int w    = tid >> 6;    // wave id = n-slice
    int lane = tid & 63;

    floatx4 acc[4][4];
#pragma unroll
    for (int ms = 0; ms < 4; ms++)
#pragma unroll
        for (int nn = 0; nn < 4; nn++) {
            acc[ms][nn][0] = 0.f; acc[ms][nn][1] = 0.f;
            acc[ms][nn][2] = 0.f; acc[ms][nn][3] = 0.f;
        }

    for (int ks = 0; ks < 8; ks++) {
        half8 bfrag[4];
#pragma unroll
        for (int nn = 0; nn < 4; nn++)
            bfrag[nn] = Bswz[((w * 4 + nn) * 8 + ks) * 64 + lane];
        half8 afrag[4];
#pragma unroll
        for (int ms = 0; ms < 4; ms++)
            afrag[ms] = *(const half8*)((char*)As +
                            As_swz(((ms * 8 + ks) * 64 + lane) * 16));
#pragma unroll
        for (int ms = 0; ms < 4; ms++)
#pragma unroll
            for (int nn = 0; nn < 4; nn++)
                acc[ms][nn] = __builtin_amdgcn_mfma_f32_16x16x32_f16(
                    afrag[ms], bfrag[nn], acc[ms][nn], 0, 0, 0);
    }

    // epilogue: C/D layout col=lane&15, row=(lane>>4)*4+i
    int rgrp = lane >> 4;
    int cl   = lane & 15;
#pragma unroll
    for (int ms = 0; ms < 4; ms++) {
        int rbase = row0 + ms * 16 + rgrp * 4;
        float nrm[4];
#pragma unroll
        for (int i = 0; i < 4; i++) {
            int r = rbase + i;
            nrm[i] = (r < n) ? rsqrtf(1.0f + (float)(rs[r + 1] - rs[r])) : 0.f;
        }
#pragma unroll
        for (int nn = 0; nn < 4; nn++) {
            int col = w * 64 + nn * 16 + cl;
            float bb = bias[col];
#pragma unroll
            for (int i = 0; i < 4; i++) {
                int r = rbase + i;
                if (r < n)
                    h16[(size_t)r * 256 + col] =
                        (_Float16)((acc[ms][nn][i] + bb) * nrm[i]);
            }
        }
    }
}

// ---------------- aggregation over one feature half (128 cols) ----------------
// Wave per row; quarter-wave (16 lanes x 16B) per edge, 4 edges in flight.
__global__ __launch_bounds__(THREADS) void agg_half(
    const _Float16* __restrict__ h16, const int* __restrict__ csr_col,
    const int* __restrict__ rs, float* __restrict__ out, int n, int halfsel) {
    int row = blockIdx.x * 4 + (threadIdx.x >> 6);
    if (row >= n) return;
    int lane = threadIdx.x & 63;
    int g    = lane >> 4;            // edge group 0..3
    int l16  = lane & 15;
    int off  = halfsel * 128 + l16 * 8;   // 8 f16 cols per lane
    const _Float16* hb = h16 + off;

    int s   = rs[row];
    int end = rs[row + 1];

    float acc[8] = {0.f, 0.f, 0.f, 0.f, 0.f, 0.f, 0.f, 0.f};
    if (g == 0) {   // residual h_scaled[row] for this half
        half8 v = *(const half8*)(hb + (size_t)row * 256);
#pragma unroll
        for (int j = 0; j < 8; j++) acc[j] = (float)v[j];
    }

    int e = s + g;   // group g takes edges s+g, s+g+4, ...
    for (; e + 4 < end; e += 8) {
        int c0 = csr_col[e];
        int c1 = csr_col[e + 4];
        half8 v0 = *(const half8*)(hb + (size_t)c0 * 256);
        half8 v1 = *(const half8*)(hb + (size_t)c1 * 256);
#pragma unroll
        for (int j = 0; j < 8; j++) acc[j] += (float)v0[j] + (float)v1[j];
    }
    for (; e < end; e += 4) {
        int c = csr_col[e];
        half8 v = *(const half8*)(hb + (size_t)c * 256);
#pragma unroll
        for (int j = 0; j < 8; j++) acc[j] += (float)v[j];
    }

    // cross-group reduction: 4 groups -> group 0
#pragma unroll
    for (int j = 0; j < 8; j++) acc[j] += __shfl_down(acc[j], 32);
#pragma unroll
    for (int j = 0; j < 8; j++) acc[j] += __shfl_down(acc[j], 16);

    if (g == 0) {
        float nrm = rsqrtf(1.0f + (float)(end - s));
        float4 o0, o1;
        o0.x = acc[0] * nrm; o0.y = acc[1] * nrm; o0.z = acc[2] * nrm; o0.w = acc[3] * nrm;
        o1.x = acc[4] * nrm; o1.y = acc[5] * nrm; o1.z = acc[6] * nrm; o1.w = acc[7] * nrm;
        float* dst = out + (size_t)row * 256 + off;
        *(float4*)dst       = o0;
        *(float4*)(dst + 4) = o1;
    }
}

// ---------------------------------------------------------------------------
extern "C" void kernel_launch(void* const* d_in, const int* in_sizes, int n_in,
                              void* d_out, int out_size, void* d_ws, size_t ws_size,
                              hipStream_t stream) {
    const float* x    = (const float*)d_in[0];
    const float* W    = (const float*)d_in[1];
    const float* bias = (const float*)d_in[2];
    const int*   rows = (const int*)d_in[3];
    const int*   cols = (const int*)d_in[4];

    const int D = 256;
    int n = in_sizes[0] / D;    // 100000
    int E = in_sizes[3];        // 3200000

    // ---- workspace carve ----
    char* p = (char*)d_ws;
    auto alignup = [](size_t v) { return (v + 255) & ~(size_t)255; };
    _Float16* h16 = (_Float16*)p; p += alignup((size_t)n * D * sizeof(_Float16)); // 51.2 MB
    int*   cnt    = (int*)p;    p += alignup((size_t)n * sizeof(int));
    int*   rs     = (int*)p;    p += alignup((size_t)(n + 1) * sizeof(int));
    int*   bsums  = (int*)p;    p += alignup((size_t)1024);
    int*   csr    = (int*)p;    p += alignup((size_t)E * sizeof(int));            // 12.8 MB
    half8* Bswz   = (half8*)p;  p += alignup((size_t)8192 * sizeof(half8));       // 128 KB

    // rank[] overlays the h16 region (12.8 MB << 51.2 MB); h16 is written
    // by gemm only AFTER scatter2 has consumed rank.
    int* rank = (int*)h16;

    hipMemsetAsync(cnt, 0, (size_t)n * sizeof(int), stream);

    int e8blocks = ((E + 7) / 8 + THREADS - 1) / THREADS;   // 1563
    rank_kernel<<<e8blocks, THREADS, 0, stream>>>(rows, cnt, rank, E);

    int nb = (n + 1023) / 1024;  // 98 <= 256
    scanA<<<nb, THREADS, 0, stream>>>(cnt, rs, bsums, n);
    scanB<<<1, THREADS, 0, stream>>>(bsums, nb);
    scanC<<<nb, THREADS, 0, stream>>>(rs, bsums, n, E);

    int e4blocks = ((E + 3) / 4 + THREADS - 1) / THREADS;   // 3125
    scatter2<<<e4blocks, THREADS, 0, stream>>>(rows, cols, rank, rs, csr, E);

    make_bswz<<<32, THREADS, 0, stream>>>(W, Bswz);

    int gblocks = (n + 63) / 64;   // 1563
    gemm_mfma<<<gblocks, THREADS, 0, stream>>>(x, Bswz, bias, rs, h16, n);

    int ablocks = (n + 3) / 4;     // 25000
    agg_half<<<ablocks, THREADS, 0, stream>>>(h16, csr, rs, (float*)d_out, n, 0);
    agg_half<<<ablocks, THREADS, 0, stream>>>(h16, csr, rs, (float*)d_out, n, 1);
}

// Round 4
// 570.805 us; speedup vs baseline: 1.1824x; 1.1824x over previous
//
#include <hip/hip_runtime.h>
#include <hip/hip_fp16.h>
#include <stdint.h>

// ---------------------------------------------------------------------------
// GraphConv (planetoid-gcn-residual):
//   h   = norm * (x @ W.T + bias),  norm = rsqrt(1+deg)
//   out = norm * (spmm_add(adj,h) + h)
// R3 (743.6 -> 666.9): single atomic rank pass, atomic-free scatter, gemm LDS
//   swizzle, agg split in 2.
// R5 (FAILED, 674.9): 8 atomics/lane in flight made rank SLOWER -> memory-side
//   atomic THROUGHPUT bound (~21 ops/ns device-wide), not latency.
// R6: atomic-free(-ish) CSR build via bucketed counting sort.
//   bucket = row>>7 partitions rows (128 rows/bucket, 782 buckets, ~4K edges).
//   B1: LDS bucket histogram, 256 blocks -> ~200K bulk global atomics.
//   B2: scan 782 bucket counts (1 block) -> boff; init reservation cursors.
//   B3: per-block LDS hist + ONE reservation atomic per (block,bucket)
//       (~153K), then place edges (row,col) grouped-by-bucket into buf.
//   B5: block per bucket: LDS row-hist + LDS scan -> writes rs directly
//       (rs[row] = boff[b] + prefix; global row scan ELIMINATED) and scatters
//       cols to final CSR with LDS cursors. Zero global atomics.
//   rank/scanA/B/C/scatter2 all deleted. gemm/agg unchanged.
// ---------------------------------------------------------------------------

#define THREADS 256
#define MAXBUCK 800            // ceil(100000/128)=782 <= 800
#define B3_EDGES 16384

typedef _Float16 half8 __attribute__((ext_vector_type(8)));
typedef float floatx4 __attribute__((ext_vector_type(4)));

// ---------------- B1: bucket histogram (LDS) + bulk global merge ----------------
__global__ __launch_bounds__(THREADS) void bucket_count(
    const int* __restrict__ rows, int* __restrict__ bcnt, int E, int nbuck) {
    __shared__ int h[MAXBUCK];
    for (int b = threadIdx.x; b < nbuck; b += THREADS) h[b] = 0;
    __syncthreads();
    int nquad  = E >> 2;
    int stride = gridDim.x * THREADS;
    for (int q = blockIdx.x * THREADS + threadIdx.x; q < nquad; q += stride) {
        int4 r = ((const int4*)rows)[q];
        atomicAdd(&h[r.x >> 7], 1);
        atomicAdd(&h[r.y >> 7], 1);
        atomicAdd(&h[r.z >> 7], 1);
        atomicAdd(&h[r.w >> 7], 1);
    }
    if (blockIdx.x == 0)
        for (int e = (nquad << 2) + threadIdx.x; e < E; e += THREADS)
            atomicAdd(&h[rows[e] >> 7], 1);
    __syncthreads();
    for (int b = threadIdx.x; b < nbuck; b += THREADS) {
        int v = h[b];
        if (v) atomicAdd(&bcnt[b], v);
    }
}

// ---------------- B2: exclusive scan over bucket counts (1 block) ----------------
__global__ __launch_bounds__(THREADS) void bucket_scan(
    const int* __restrict__ bcnt, int* __restrict__ boff, int* __restrict__ bcur,
    int nbuck, int E) {
    __shared__ int s[THREADS];
    int tid = threadIdx.x;
    int i0  = tid * 4;
    int v0 = (i0 + 0 < nbuck) ? bcnt[i0 + 0] : 0;
    int v1 = (i0 + 1 < nbuck) ? bcnt[i0 + 1] : 0;
    int v2 = (i0 + 2 < nbuck) ? bcnt[i0 + 2] : 0;
    int v3 = (i0 + 3 < nbuck) ? bcnt[i0 + 3] : 0;
    int sum = v0 + v1 + v2 + v3;
    s[tid] = sum;
    __syncthreads();
    for (int off = 1; off < THREADS; off <<= 1) {
        int t = (tid >= off) ? s[tid - off] : 0;
        __syncthreads();
        s[tid] += t;
        __syncthreads();
    }
    int run = s[tid] - sum;
    if (i0 + 0 < nbuck) { boff[i0 + 0] = run; bcur[i0 + 0] = run; }  run += v0;
    if (i0 + 1 < nbuck) { boff[i0 + 1] = run; bcur[i0 + 1] = run; }  run += v1;
    if (i0 + 2 < nbuck) { boff[i0 + 2] = run; bcur[i0 + 2] = run; }  run += v2;
    if (i0 + 3 < nbuck) { boff[i0 + 3] = run; bcur[i0 + 3] = run; }
    if (tid == 0) boff[nbuck] = E;
}

// ---------------- B3: bucket-grouping scatter, 1 reservation atomic/bucket ----------------
__global__ __launch_bounds__(THREADS) void bucket_scatter(
    const int* __restrict__ rows, const int* __restrict__ cols,
    int* __restrict__ bcur, int2* __restrict__ buf, int E, int nbuck) {
    __shared__ int h[MAXBUCK];
    __shared__ int lbase[MAXBUCK];
    for (int b = threadIdx.x; b < nbuck; b += THREADS) h[b] = 0;
    __syncthreads();
    int e0 = blockIdx.x * B3_EDGES;
    int e1 = e0 + B3_EDGES; if (e1 > E) e1 = E;
    for (int e = e0 + threadIdx.x; e < e1; e += THREADS)
        atomicAdd(&h[rows[e] >> 7], 1);
    __syncthreads();
    for (int b = threadIdx.x; b < nbuck; b += THREADS) {
        int v = h[b];
        lbase[b] = v ? atomicAdd(&bcur[b], v) : 0;
        h[b] = 0;                       // reuse as local cursor
    }
    __syncthreads();
    for (int e = e0 + threadIdx.x; e < e1; e += THREADS) {
        int r = rows[e];
        int c = cols[e];
        int b = r >> 7;
        int p = lbase[b] + atomicAdd(&h[b], 1);
        buf[p] = make_int2(r, c);
    }
}

// ---------------- B5: per-bucket CSR finalize + rs (block owns 128 rows) ----------------
__global__ __launch_bounds__(THREADS) void csr_finalize(
    const int2* __restrict__ buf, const int* __restrict__ boff,
    int* __restrict__ rs, int* __restrict__ csr, int n, int E) {
    int b = blockIdx.x;
    __shared__ int h[128];
    __shared__ int base[128];
    if (threadIdx.x < 128) h[threadIdx.x] = 0;
    __syncthreads();
    int s = boff[b], e = boff[b + 1];
    for (int i = s + threadIdx.x; i < e; i += THREADS)
        atomicAdd(&h[buf[i].x & 127], 1);
    __syncthreads();
    if (threadIdx.x < 128) base[threadIdx.x] = h[threadIdx.x];
    __syncthreads();
    for (int off = 1; off < 128; off <<= 1) {
        int t = 0;
        if (threadIdx.x < 128 && threadIdx.x >= off) t = base[threadIdx.x - off];
        __syncthreads();
        if (threadIdx.x < 128) base[threadIdx.x] += t;
        __syncthreads();
    }
    if (threadIdx.x < 128) {
        int excl = s + base[threadIdx.x] - h[threadIdx.x];   // exclusive + bucket base
        base[threadIdx.x] = excl;
        int row = (b << 7) + threadIdx.x;
        if (row < n) rs[row] = excl;
        h[threadIdx.x] = 0;                                  // reuse as cursor
    }
    if (b == 0 && threadIdx.x == 0) rs[n] = E;
    __syncthreads();
    for (int i = s + threadIdx.x; i < e; i += THREADS) {
        int2 rc = buf[i];
        int rl = rc.x & 127;
        int p = base[rl] + atomicAdd(&h[rl], 1);
        csr[p] = rc.y;
    }
}

// ---------------- W -> f16 B-fragment swizzle ----------------
__global__ void make_bswz(const float* __restrict__ W, half8* __restrict__ Bswz) {
    int t = blockIdx.x * THREADS + threadIdx.x;   // 8192 entries
    int n_tile = t >> 9;
    int k_step = (t >> 6) & 7;
    int lane   = t & 63;
    int q = lane >> 4, m16 = lane & 15;
    const float* src = W + (size_t)(n_tile * 16 + m16) * 256 + k_step * 32 + q * 8;
    half8 h;
#pragma unroll
    for (int j = 0; j < 8; j++) h[j] = (_Float16)src[j];
    Bswz[t] = h;
}

// LDS byte-address swizzle: spread k_step (bits 10-12) and q-parity (bit 8)
// into bits 4-7 so staging writes hit all banks (was ~32-way conflict).
__device__ __forceinline__ int As_swz(int b) {
    return b ^ ((((b >> 10) & 7) ^ (((b >> 8) & 1) << 3)) << 4);
}

// ---------------- f16 MFMA GEMM + bias + norm scale ----------------
// Block: 256 thr = 4 waves. Tile: 64 rows x 256 cols; wave w -> cols [64w,64w+64).
__global__ __launch_bounds__(THREADS) void gemm_mfma(
    const float* __restrict__ x, const half8* __restrict__ Bswz,
    const float* __restrict__ bias, const int* __restrict__ rs,
    _Float16* __restrict__ h16, int n) {
    __shared__ _Float16 As[4 * 8 * 64 * 8];   // 32 KB, A-frag layout (swizzled)
    int tid  = threadIdx.x;
    int row0 = blockIdx.x * 64;

    // stage x tile fp32 -> f16 into (swizzled) A-frag layout
#pragma unroll
    for (int i = 0; i < 16; i++) {
        int flat = i * THREADS + tid;
        int r  = flat >> 6;         // 0..63 row in tile
        int k  = (flat & 63) * 4;   // 0..252 step 4
        float4 v;
        if (row0 + r < n) v = *(const float4*)(x + (size_t)(row0 + r) * 256 + k);
        else { v.x = 0.f; v.y = 0.f; v.z = 0.f; v.w = 0.f; }
        int m_sub  = r >> 4;
        int k_step = k >> 5;
        int q      = (k >> 3) & 3;
        int j      = k & 7;         // 0 or 4
        int lane_w = (r & 15) + (q << 4);
        int entry  = (m_sub * 8 + k_step) * 64 + lane_w;
        union { _Float16 h[4]; uint2 u; } pk;
        pk.h[0] = (_Float16)v.x; pk.h[1] = (_Float16)v.y;
        pk.h[2] = (_Float16)v.z; pk.h[3] = (_Float16)v.w;
        *(uint2*)((char*)As + As_swz(entry * 16 + (j << 1))) = pk.u;
    }
    __syncthreads();

    int w    = tid >> 6;    // wave id = n-slice
    int lane = tid & 63;

    floatx4 acc[4][4];
#pragma unroll
    for (int ms = 0; ms < 4; ms++)
#pragma unroll
        for (int nn = 0; nn < 4; nn++) {
            acc[ms][nn][0] = 0.f; acc[ms][nn][1] = 0.f;
            acc[ms][nn][2] = 0.f; acc[ms][nn][3] = 0.f;
        }

    for (int ks = 0; ks < 8; ks++) {
        half8 bfrag[4];
#pragma unroll
        for (int nn = 0; nn < 4; nn++)
            bfrag[nn] = Bswz[((w * 4 + nn) * 8 + ks) * 64 + lane];
        half8 afrag[4];
#pragma unroll
        for (int ms = 0; ms < 4; ms++)
            afrag[ms] = *(const half8*)((char*)As +
                            As_swz(((ms * 8 + ks) * 64 + lane) * 16));
#pragma unroll
        for (int ms = 0; ms < 4; ms++)
#pragma unroll
            for (int nn = 0; nn < 4; nn++)
                acc[ms][nn] = __builtin_amdgcn_mfma_f32_16x16x32_f16(
                    afrag[ms], bfrag[nn], acc[ms][nn], 0, 0, 0);
    }

    // epilogue: C/D layout col=lane&15, row=(lane>>4)*4+i
    int rgrp = lane >> 4;
    int cl   = lane & 15;
#pragma unroll
    for (int ms = 0; ms < 4; ms++) {
        int rbase = row0 + ms * 16 + rgrp * 4;
        float nrm[4];
#pragma unroll
        for (int i = 0; i < 4; i++) {
            int r = rbase + i;
            nrm[i] = (r < n) ? rsqrtf(1.0f + (float)(rs[r + 1] - rs[r])) : 0.f;
        }
#pragma unroll
        for (int nn = 0; nn < 4; nn++) {
            int col = w * 64 + nn * 16 + cl;
            float bb = bias[col];
#pragma unroll
            for (int i = 0; i < 4; i++) {
                int r = rbase + i;
                if (r < n)
                    h16[(size_t)r * 256 + col] =
                        (_Float16)((acc[ms][nn][i] + bb) * nrm[i]);
            }
        }
    }
}

// ---------------- aggregation over one feature half (128 cols) ----------------
// Wave per row; quarter-wave (16 lanes x 16B) per edge, 4 edges in flight.
__global__ __launch_bounds__(THREADS) void agg_half(
    const _Float16* __restrict__ h16, const int* __restrict__ csr_col,
    const int* __restrict__ rs, float* __restrict__ out, int n, int halfsel) {
    int row = blockIdx.x * 4 + (threadIdx.x >> 6);
    if (row >= n) return;
    int lane = threadIdx.x & 63;
    int g    = lane >> 4;            // edge group 0..3
    int l16  = lane & 15;
    int off  = halfsel * 128 + l16 * 8;   // 8 f16 cols per lane
    const _Float16* hb = h16 + off;

    int s   = rs[row];
    int end = rs[row + 1];

    float acc[8] = {0.f, 0.f, 0.f, 0.f, 0.f, 0.f, 0.f, 0.f};
    if (g == 0) {   // residual h_scaled[row] for this half
        half8 v = *(const half8*)(hb + (size_t)row * 256);
#pragma unroll
        for (int j = 0; j < 8; j++) acc[j] = (float)v[j];
    }

    int e = s + g;   // group g takes edges s+g, s+g+4, ...
    for (; e + 4 < end; e += 8) {
        int c0 = csr_col[e];
        int c1 = csr_col[e + 4];
        half8 v0 = *(const half8*)(hb + (size_t)c0 * 256);
        half8 v1 = *(const half8*)(hb + (size_t)c1 * 256);
#pragma unroll
        for (int j = 0; j < 8; j++) acc[j] += (float)v0[j] + (float)v1[j];
    }
    for (; e < end; e += 4) {
        int c = csr_col[e];
        half8 v = *(const half8*)(hb + (size_t)c * 256);
#pragma unroll
        for (int j = 0; j < 8; j++) acc[j] += (float)v[j];
    }

    // cross-group reduction: 4 groups -> group 0
#pragma unroll
    for (int j = 0; j < 8; j++) acc[j] += __shfl_down(acc[j], 32);
#pragma unroll
    for (int j = 0; j < 8; j++) acc[j] += __shfl_down(acc[j], 16);

    if (g == 0) {
        float nrm = rsqrtf(1.0f + (float)(end - s));
        float4 o0, o1;
        o0.x = acc[0] * nrm; o0.y = acc[1] * nrm; o0.z = acc[2] * nrm; o0.w = acc[3] * nrm;
        o1.x = acc[4] * nrm; o1.y = acc[5] * nrm; o1.z = acc[6] * nrm; o1.w = acc[7] * nrm;
        float* dst = out + (size_t)row * 256 + off;
        *(float4*)dst       = o0;
        *(float4*)(dst + 4) = o1;
    }
}

// ---------------------------------------------------------------------------
extern "C" void kernel_launch(void* const* d_in, const int* in_sizes, int n_in,
                              void* d_out, int out_size, void* d_ws, size_t ws_size,
                              hipStream_t stream) {
    const float* x    = (const float*)d_in[0];
    const float* W    = (const float*)d_in[1];
    const float* bias = (const float*)d_in[2];
    const int*   rows = (const int*)d_in[3];
    const int*   cols = (const int*)d_in[4];

    const int D = 256;
    int n = in_sizes[0] / D;    // 100000
    int E = in_sizes[3];        // 3200000
    int nbuck = (n + 127) >> 7; // 782 (<= MAXBUCK)

    // ---- workspace carve ----
    char* p = (char*)d_ws;
    auto alignup = [](size_t v) { return (v + 255) & ~(size_t)255; };
    _Float16* h16 = (_Float16*)p; p += alignup((size_t)n * D * sizeof(_Float16)); // 51.2 MB
    int*   rs     = (int*)p;    p += alignup((size_t)(n + 1) * sizeof(int));
    int*   csr    = (int*)p;    p += alignup((size_t)E * sizeof(int));            // 12.8 MB
    half8* Bswz   = (half8*)p;  p += alignup((size_t)8192 * sizeof(half8));       // 128 KB
    int*   bcnt   = (int*)p;    p += alignup((size_t)MAXBUCK * sizeof(int));
    int*   boff   = (int*)p;    p += alignup((size_t)(MAXBUCK + 1) * sizeof(int));
    int*   bcur   = (int*)p;    p += alignup((size_t)MAXBUCK * sizeof(int));

    // buf[] (int2 per edge, 25.6 MB) overlays the h16 region (51.2 MB); h16 is
    // written by gemm only AFTER csr_finalize has consumed buf.
    int2* buf = (int2*)h16;

    hipMemsetAsync(bcnt, 0, (size_t)nbuck * sizeof(int), stream);

    bucket_count<<<256, THREADS, 0, stream>>>(rows, bcnt, E, nbuck);
    bucket_scan<<<1, THREADS, 0, stream>>>(bcnt, boff, bcur, nbuck, E);

    int b3blocks = (E + B3_EDGES - 1) / B3_EDGES;   // 196
    bucket_scatter<<<b3blocks, THREADS, 0, stream>>>(rows, cols, bcur, buf, E, nbuck);

    csr_finalize<<<nbuck, THREADS, 0, stream>>>(buf, boff, rs, csr, n, E);

    make_bswz<<<32, THREADS, 0, stream>>>(W, Bswz);

    int gblocks = (n + 63) / 64;   // 1563
    gemm_mfma<<<gblocks, THREADS, 0, stream>>>(x, Bswz, bias, rs, h16, n);

    int ablocks = (n + 3) / 4;     // 25000
    agg_half<<<ablocks, THREADS, 0, stream>>>(h16, csr, rs, (float*)d_out, n, 0);
    agg_half<<<ablocks, THREADS, 0, stream>>>(h16, csr, rs, (float*)d_out, n, 1);
}

// Round 5
// 548.773 us; speedup vs baseline: 1.2298x; 1.0401x over previous
//
#include <hip/hip_runtime.h>
#include <hip/hip_fp16.h>
#include <stdint.h>

// ---------------------------------------------------------------------------
// GraphConv (planetoid-gcn-residual):
//   h   = norm * (x @ W.T + bias),  norm = rsqrt(1+deg)
//   out = norm * (spmm_add(adj,h) + h)
// R6 (674.9 -> 570.8): bucketed counting-sort CSR build (128-row buckets),
//   global atomics ~3.2M -> ~350K. Top-5 now pure agg_half (112us x2).
// R7: hidden ~347us suspected in B3's 8B random scatter (~205MB effective
//   write traffic at 64B line granularity). Changes:
//   - buckets 128 -> 512 rows (nbuck=196); edge packed to 4B:
//     (r&511)<<17 | c  (c < 2^17). buf traffic halves both directions.
//   - B3: LDS counting-sort (8K edges staged bucket-ordered in 32KB LDS),
//     flush per-bucket lane-coalesced -> writes ~12.8MB effective, not 205MB.
//   - B5: 512-row blocks, 512-bin LDS hist + scan, packed buf read.
//   - agg_half: nontemporal out stores (100MB streaming writes were evicting
//     h16 gather lines from L2; keep L2 for the gather).
//   gemm/make_bswz unchanged.
// ---------------------------------------------------------------------------

#define THREADS 256
#define NB 256             // padded bucket array size (nbuck = 196)
#define B3_EDGES 8192

typedef _Float16 half8 __attribute__((ext_vector_type(8)));
typedef float floatx4 __attribute__((ext_vector_type(4)));

// ---------------- B1: bucket histogram (LDS) + bulk global merge ----------------
__global__ __launch_bounds__(THREADS) void bucket_count(
    const int* __restrict__ rows, int* __restrict__ bcnt, int E, int nbuck) {
    __shared__ int h[NB];
    h[threadIdx.x] = 0;
    __syncthreads();
    int nquad  = E >> 2;
    int stride = gridDim.x * THREADS;
    for (int q = blockIdx.x * THREADS + threadIdx.x; q < nquad; q += stride) {
        int4 r = ((const int4*)rows)[q];
        atomicAdd(&h[r.x >> 9], 1);
        atomicAdd(&h[r.y >> 9], 1);
        atomicAdd(&h[r.z >> 9], 1);
        atomicAdd(&h[r.w >> 9], 1);
    }
    if (blockIdx.x == 0)
        for (int e = (nquad << 2) + threadIdx.x; e < E; e += THREADS)
            atomicAdd(&h[rows[e] >> 9], 1);
    __syncthreads();
    int v = h[threadIdx.x];
    if (threadIdx.x < nbuck && v) atomicAdd(&bcnt[threadIdx.x], v);
}

// ---------------- B2: exclusive scan over bucket counts (1 block) ----------------
__global__ __launch_bounds__(THREADS) void bucket_scan(
    const int* __restrict__ bcnt, int* __restrict__ boff, int* __restrict__ bcur,
    int nbuck, int E) {
    __shared__ int s[THREADS];
    int tid = threadIdx.x;
    int v = (tid < nbuck) ? bcnt[tid] : 0;
    s[tid] = v;
    __syncthreads();
    for (int off = 1; off < THREADS; off <<= 1) {
        int t = (tid >= off) ? s[tid - off] : 0;
        __syncthreads();
        s[tid] += t;
        __syncthreads();
    }
    int excl = s[tid] - v;
    if (tid < nbuck) { boff[tid] = excl; bcur[tid] = excl; }
    if (tid == 0) boff[nbuck] = E;
}

// ---------------- B3: LDS counting-sort into bucket-grouped packed buf ----------------
// 8K edges/block staged bucket-ordered in LDS, flushed coalesced per bucket.
__global__ __launch_bounds__(THREADS) void bucket_scatter(
    const int* __restrict__ rows, const int* __restrict__ cols,
    int* __restrict__ bcur, uint32_t* __restrict__ buf, int E, int nbuck) {
    __shared__ uint32_t staged[B3_EDGES];   // 32 KB
    __shared__ int h[NB], lo[NB], gb[NB], hc[NB];
    int tid = threadIdx.x;
    h[tid] = 0; hc[tid] = 0;
    __syncthreads();
    int e0 = blockIdx.x * B3_EDGES;
    int e1 = e0 + B3_EDGES; if (e1 > E) e1 = E;
    // phase 1: local bucket histogram
    for (int e = e0 + tid; e < e1; e += THREADS)
        atomicAdd(&h[rows[e] >> 9], 1);
    __syncthreads();
    // phase 2: LDS exclusive scan over NB buckets + global reservation
    int v = h[tid];
    lo[tid] = v;
    __syncthreads();
    for (int off = 1; off < NB; off <<= 1) {
        int t = (tid >= off) ? lo[tid - off] : 0;
        __syncthreads();
        lo[tid] += t;
        __syncthreads();
    }
    int excl = lo[tid] - v;
    __syncthreads();
    lo[tid] = excl;
    gb[tid] = (tid < nbuck && v) ? atomicAdd(&bcur[tid], v) : 0;
    __syncthreads();
    // phase 3: place edges bucket-ordered into LDS (packed 4B: rl<<17 | c)
    for (int e = e0 + tid; e < e1; e += THREADS) {
        int r = rows[e];
        int c = cols[e];
        int b = r >> 9;
        int p = lo[b] + atomicAdd(&hc[b], 1);
        staged[p] = ((uint32_t)(r & 511) << 17) | (uint32_t)c;
    }
    __syncthreads();
    // phase 4: coalesced flush, one wave per bucket round-robin
    int wid = tid >> 6, lane = tid & 63;
    for (int b = wid; b < nbuck; b += 4) {
        int cnt = h[b], src = lo[b], dst = gb[b];
        for (int i = lane; i < cnt; i += 64)
            buf[dst + i] = staged[src + i];
    }
}

// ---------------- B5: per-bucket CSR finalize + rs (block owns 512 rows) ----------------
__global__ __launch_bounds__(THREADS) void csr_finalize(
    const uint32_t* __restrict__ buf, const int* __restrict__ boff,
    int* __restrict__ rs, int* __restrict__ csr, int n, int E) {
    int b   = blockIdx.x;
    int tid = threadIdx.x;
    __shared__ int h[512], base[512], s1[THREADS];
    h[tid] = 0; h[tid + 256] = 0;
    __syncthreads();
    int s = boff[b], e = boff[b + 1];
    for (int i = s + tid; i < e; i += THREADS)
        atomicAdd(&h[buf[i] >> 17], 1);
    __syncthreads();
    // 512-bin exclusive scan: pair-reduce then 256-scan
    int a0 = h[2 * tid], a1 = h[2 * tid + 1];
    s1[tid] = a0 + a1;
    __syncthreads();
    for (int off = 1; off < THREADS; off <<= 1) {
        int t = (tid >= off) ? s1[tid - off] : 0;
        __syncthreads();
        s1[tid] += t;
        __syncthreads();
    }
    int eps = s1[tid] - (a0 + a1);
    base[2 * tid]     = s + eps;
    base[2 * tid + 1] = s + eps + a0;
    __syncthreads();
#pragma unroll
    for (int j = 0; j < 2; j++) {
        int rl  = tid + j * 256;
        int row = (b << 9) + rl;
        if (row < n) rs[row] = base[rl];
        h[rl] = 0;                        // reuse as cursor
    }
    if (b == 0 && tid == 0) rs[n] = E;
    __syncthreads();
    for (int i = s + tid; i < e; i += THREADS) {
        uint32_t v = buf[i];
        int rl = v >> 17;
        int c  = v & 0x1FFFF;
        int p  = base[rl] + atomicAdd(&h[rl], 1);
        csr[p] = c;
    }
}

// ---------------- W -> f16 B-fragment swizzle ----------------
__global__ void make_bswz(const float* __restrict__ W, half8* __restrict__ Bswz) {
    int t = blockIdx.x * THREADS + threadIdx.x;   // 8192 entries
    int n_tile = t >> 9;
    int k_step = (t >> 6) & 7;
    int lane   = t & 63;
    int q = lane >> 4, m16 = lane & 15;
    const float* src = W + (size_t)(n_tile * 16 + m16) * 256 + k_step * 32 + q * 8;
    half8 h;
#pragma unroll
    for (int j = 0; j < 8; j++) h[j] = (_Float16)src[j];
    Bswz[t] = h;
}

// LDS byte-address swizzle: spread k_step (bits 10-12) and q-parity (bit 8)
// into bits 4-7 so staging writes hit all banks (was ~32-way conflict).
__device__ __forceinline__ int As_swz(int b) {
    return b ^ ((((b >> 10) & 7) ^ (((b >> 8) & 1) << 3)) << 4);
}

// ---------------- f16 MFMA GEMM + bias + norm scale ----------------
// Block: 256 thr = 4 waves. Tile: 64 rows x 256 cols; wave w -> cols [64w,64w+64).
__global__ __launch_bounds__(THREADS) void gemm_mfma(
    const float* __restrict__ x, const half8* __restrict__ Bswz,
    const float* __restrict__ bias, const int* __restrict__ rs,
    _Float16* __restrict__ h16, int n) {
    __shared__ _Float16 As[4 * 8 * 64 * 8];   // 32 KB, A-frag layout (swizzled)
    int tid  = threadIdx.x;
    int row0 = blockIdx.x * 64;

    // stage x tile fp32 -> f16 into (swizzled) A-frag layout
#pragma unroll
    for (int i = 0; i < 16; i++) {
        int flat = i * THREADS + tid;
        int r  = flat >> 6;         // 0..63 row in tile
        int k  = (flat & 63) * 4;   // 0..252 step 4
        float4 v;
        if (row0 + r < n) v = *(const float4*)(x + (size_t)(row0 + r) * 256 + k);
        else { v.x = 0.f; v.y = 0.f; v.z = 0.f; v.w = 0.f; }
        int m_sub  = r >> 4;
        int k_step = k >> 5;
        int q      = (k >> 3) & 3;
        int j      = k & 7;         // 0 or 4
        int lane_w = (r & 15) + (q << 4);
        int entry  = (m_sub * 8 + k_step) * 64 + lane_w;
        union { _Float16 h[4]; uint2 u; } pk;
        pk.h[0] = (_Float16)v.x; pk.h[1] = (_Float16)v.y;
        pk.h[2] = (_Float16)v.z; pk.h[3] = (_Float16)v.w;
        *(uint2*)((char*)As + As_swz(entry * 16 + (j << 1))) = pk.u;
    }
    __syncthreads();

    int w    = tid >> 6;    // wave id = n-slice
    int lane = tid & 63;

    floatx4 acc[4][4];
#pragma unroll
    for (int ms = 0; ms < 4; ms++)
#pragma unroll
        for (int nn = 0; nn < 4; nn++) {
            acc[ms][nn][0] = 0.f; acc[ms][nn][1] = 0.f;
            acc[ms][nn][2] = 0.f; acc[ms][nn][3] = 0.f;
        }

    for (int ks = 0; ks < 8; ks++) {
        half8 bfrag[4];
#pragma unroll
        for (int nn = 0; nn < 4; nn++)
            bfrag[nn] = Bswz[((w * 4 + nn) * 8 + ks) * 64 + lane];
        half8 afrag[4];
#pragma unroll
        for (int ms = 0; ms < 4; ms++)
            afrag[ms] = *(const half8*)((char*)As +
                            As_swz(((ms * 8 + ks) * 64 + lane) * 16));
#pragma unroll
        for (int ms = 0; ms < 4; ms++)
#pragma unroll
            for (int nn = 0; nn < 4; nn++)
                acc[ms][nn] = __builtin_amdgcn_mfma_f32_16x16x32_f16(
                    afrag[ms], bfrag[nn], acc[ms][nn], 0, 0, 0);
    }

    // epilogue: C/D layout col=lane&15, row=(lane>>4)*4+i
    int rgrp = lane >> 4;
    int cl   = lane & 15;
#pragma unroll
    for (int ms = 0; ms < 4; ms++) {
        int rbase = row0 + ms * 16 + rgrp * 4;
        float nrm[4];
#pragma unroll
        for (int i = 0; i < 4; i++) {
            int r = rbase + i;
            nrm[i] = (r < n) ? rsqrtf(1.0f + (float)(rs[r + 1] - rs[r])) : 0.f;
        }
#pragma unroll
        for (int nn = 0; nn < 4; nn++) {
            int col = w * 64 + nn * 16 + cl;
            float bb = bias[col];
#pragma unroll
            for (int i = 0; i < 4; i++) {
                int r = rbase + i;
                if (r < n)
                    h16[(size_t)r * 256 + col] =
                        (_Float16)((acc[ms][nn][i] + bb) * nrm[i]);
            }
        }
    }
}

// ---------------- aggregation over one feature half (128 cols) ----------------
// Wave per row; quarter-wave (16 lanes x 16B) per edge, 4 edges in flight.
__global__ __launch_bounds__(THREADS) void agg_half(
    const _Float16* __restrict__ h16, const int* __restrict__ csr_col,
    const int* __restrict__ rs, float* __restrict__ out, int n, int halfsel) {
    int row = blockIdx.x * 4 + (threadIdx.x >> 6);
    if (row >= n) return;
    int lane = threadIdx.x & 63;
    int g    = lane >> 4;            // edge group 0..3
    int l16  = lane & 15;
    int off  = halfsel * 128 + l16 * 8;   // 8 f16 cols per lane
    const _Float16* hb = h16 + off;

    int s   = rs[row];
    int end = rs[row + 1];

    float acc[8] = {0.f, 0.f, 0.f, 0.f, 0.f, 0.f, 0.f, 0.f};
    if (g == 0) {   // residual h_scaled[row] for this half
        half8 v = *(const half8*)(hb + (size_t)row * 256);
#pragma unroll
        for (int j = 0; j < 8; j++) acc[j] = (float)v[j];
    }

    int e = s + g;   // group g takes edges s+g, s+g+4, ...
    for (; e + 4 < end; e += 8) {
        int c0 = csr_col[e];
        int c1 = csr_col[e + 4];
        half8 v0 = *(const half8*)(hb + (size_t)c0 * 256);
        half8 v1 = *(const half8*)(hb + (size_t)c1 * 256);
#pragma unroll
        for (int j = 0; j < 8; j++) acc[j] += (float)v0[j] + (float)v1[j];
    }
    for (; e < end; e += 4) {
        int c = csr_col[e];
        half8 v = *(const half8*)(hb + (size_t)c * 256);
#pragma unroll
        for (int j = 0; j < 8; j++) acc[j] += (float)v[j];
    }

    // cross-group reduction: 4 groups -> group 0
#pragma unroll
    for (int j = 0; j < 8; j++) acc[j] += __shfl_down(acc[j], 32);
#pragma unroll
    for (int j = 0; j < 8; j++) acc[j] += __shfl_down(acc[j], 16);

    if (g == 0) {
        float nrm = rsqrtf(1.0f + (float)(end - s));
        floatx4 o0, o1;
        o0[0] = acc[0] * nrm; o0[1] = acc[1] * nrm; o0[2] = acc[2] * nrm; o0[3] = acc[3] * nrm;
        o1[0] = acc[4] * nrm; o1[1] = acc[5] * nrm; o1[2] = acc[6] * nrm; o1[3] = acc[7] * nrm;
        float* dst = out + (size_t)row * 256 + off;
        // nontemporal: streaming output, keep L2 for h16 gathers
        __builtin_nontemporal_store(o0, (floatx4*)dst);
        __builtin_nontemporal_store(o1, (floatx4*)(dst + 4));
    }
}

// ---------------------------------------------------------------------------
extern "C" void kernel_launch(void* const* d_in, const int* in_sizes, int n_in,
                              void* d_out, int out_size, void* d_ws, size_t ws_size,
                              hipStream_t stream) {
    const float* x    = (const float*)d_in[0];
    const float* W    = (const float*)d_in[1];
    const float* bias = (const float*)d_in[2];
    const int*   rows = (const int*)d_in[3];
    const int*   cols = (const int*)d_in[4];

    const int D = 256;
    int n = in_sizes[0] / D;    // 100000
    int E = in_sizes[3];        // 3200000
    int nbuck = (n + 511) >> 9; // 196 (<= NB)

    // ---- workspace carve ----
    char* p = (char*)d_ws;
    auto alignup = [](size_t v) { return (v + 255) & ~(size_t)255; };
    _Float16* h16 = (_Float16*)p; p += alignup((size_t)n * D * sizeof(_Float16)); // 51.2 MB
    int*   rs     = (int*)p;    p += alignup((size_t)(n + 1) * sizeof(int));
    int*   csr    = (int*)p;    p += alignup((size_t)E * sizeof(int));            // 12.8 MB
    half8* Bswz   = (half8*)p;  p += alignup((size_t)8192 * sizeof(half8));       // 128 KB
    int*   bcnt   = (int*)p;    p += alignup((size_t)NB * sizeof(int));
    int*   boff   = (int*)p;    p += alignup((size_t)(NB + 1) * sizeof(int));
    int*   bcur   = (int*)p;    p += alignup((size_t)NB * sizeof(int));

    // buf[] (packed 4B per edge, 12.8 MB) overlays the h16 region (51.2 MB);
    // h16 is written by gemm only AFTER csr_finalize has consumed buf.
    uint32_t* buf = (uint32_t*)h16;

    hipMemsetAsync(bcnt, 0, (size_t)nbuck * sizeof(int), stream);

    bucket_count<<<256, THREADS, 0, stream>>>(rows, bcnt, E, nbuck);
    bucket_scan<<<1, THREADS, 0, stream>>>(bcnt, boff, bcur, nbuck, E);

    int b3blocks = (E + B3_EDGES - 1) / B3_EDGES;   // 391
    bucket_scatter<<<b3blocks, THREADS, 0, stream>>>(rows, cols, bcur, buf, E, nbuck);

    csr_finalize<<<nbuck, THREADS, 0, stream>>>(buf, boff, rs, csr, n, E);

    make_bswz<<<32, THREADS, 0, stream>>>(W, Bswz);

    int gblocks = (n + 63) / 64;   // 1563
    gemm_mfma<<<gblocks, THREADS, 0, stream>>>(x, Bswz, bias, rs, h16, n);

    int ablocks = (n + 3) / 4;     // 25000
    agg_half<<<ablocks, THREADS, 0, stream>>>(h16, csr, rs, (float*)d_out, n, 0);
    agg_half<<<ablocks, THREADS, 0, stream>>>(h16, csr, rs, (float*)d_out, n, 1);
}